// Round 1
// baseline (769.735 us; speedup 1.0000x reference)
//
#include <hip/hip_runtime.h>
#include <hip/hip_bf16.h>
#include <stdint.h>

#define N_NODES 4096
#define U_NODES 2048
#define R_REL 5
#define B_BASES 30
#define H0 500
#define H1 75
#define E_EDGES 262144
#define EPS_BN 1e-5f
#define K_DIM 4096
#define M_COLS 3000   // 5*500 (h) + 500 (x@root)
#define M_PAD 3072
#define NSEG (N_NODES*R_REL)  // 20480

typedef __attribute__((ext_vector_type(4))) float f32x4;
typedef __attribute__((ext_vector_type(8))) short bf16x8;

static __device__ __forceinline__ ushort bf16_bits(float f) {
    union { float f; uint32_t u; } c; c.f = f;
    uint32_t u = c.u;
    uint32_t r = (u + 0x7fffu + ((u >> 16) & 1u)) >> 16;   // RNE
    return (ushort)r;
}

static __device__ __forceinline__ void async_copy16(const ushort* g, ushort* l) {
    __builtin_amdgcn_global_load_lds((const __attribute__((address_space(1))) void*)g,
                                     (__attribute__((address_space(3))) void*)l,
                                     16, 0, 0);
}

// ---------------- x fp32 -> bf16 ----------------
__global__ void k_convert_x(const float* __restrict__ x, ushort* __restrict__ xb) {
    int i = (blockIdx.x * 256 + threadIdx.x) * 4;  // N*N divisible by 1024
    float4 v = *(const float4*)(x + i);
    ushort4 o;
    o.x = bf16_bits(v.x); o.y = bf16_bits(v.y);
    o.z = bf16_bits(v.z); o.w = bf16_bits(v.w);
    *(ushort4*)(xb + i) = o;
}

// ---------------- WallT[m][k] bf16, m = r*500+o (r<5: sum_b comp[r,b]*basis[b,k,o]; r=5: root[k,o]) ----------------
__global__ void k_make_wallT(const float* __restrict__ basis, const float* __restrict__ comp,
                             const float* __restrict__ root, ushort* __restrict__ wallT) {
    __shared__ float compl_[R_REL * B_BASES];
    __shared__ float T[32][33];
    int t = threadIdx.x;
    if (t < R_REL * B_BASES) compl_[t] = comp[t];
    __syncthreads();
    int k0 = blockIdx.x * 32, o0 = blockIdx.y * 32;
    int o_in = t & 31, k_in = t >> 5;      // k_in 0..7
    int o = o0 + o_in;
    bool ov = (o < H0);
    float acc[4][6];
    #pragma unroll
    for (int a = 0; a < 4; a++)
        #pragma unroll
        for (int r = 0; r < 6; r++) acc[a][r] = 0.f;
    for (int b = 0; b < B_BASES; b++) {
        float cw[5];
        #pragma unroll
        for (int r = 0; r < 5; r++) cw[r] = compl_[r * B_BASES + b];
        #pragma unroll
        for (int a = 0; a < 4; a++) {
            int k = k0 + a * 8 + k_in;
            float v = ov ? basis[(size_t)b * K_DIM * H0 + (size_t)k * H0 + o] : 0.f;
            #pragma unroll
            for (int r = 0; r < 5; r++) acc[a][r] += cw[r] * v;
        }
    }
    #pragma unroll
    for (int a = 0; a < 4; a++) {
        int k = k0 + a * 8 + k_in;
        acc[a][5] = ov ? root[(size_t)k * H0 + o] : 0.f;
    }
    for (int r = 0; r < 6; r++) {
        __syncthreads();
        #pragma unroll
        for (int a = 0; a < 4; a++) T[o_in][a * 8 + k_in] = acc[a][r];
        __syncthreads();
        int ro = t >> 5, ck = t & 31;
        #pragma unroll
        for (int a = 0; a < 4; a++) {
            int oo = ro + a * 8;
            int om = o0 + oo;
            if (om < H0) {
                int m = r * H0 + om;
                wallT[(size_t)m * K_DIM + k0 + ck] = bf16_bits(T[oo][ck]);
            }
        }
    }
}

// ---------------- GEMM: Hall(4096 x 3000 f32) = xb(4096x4096 bf16) @ WallT^T ----------------
__global__ __launch_bounds__(256) void k_gemm(const ushort* __restrict__ A,
                                              const ushort* __restrict__ BT,
                                              float* __restrict__ C) {
    __shared__ __align__(16) ushort As[128 * 64];
    __shared__ __align__(16) ushort Bs[128 * 64];
    int tid = threadIdx.x;
    int lane = tid & 63, wave = tid >> 6;
    int m0 = blockIdx.x * 128, n0 = blockIdx.y * 128;
    int wm = (wave & 1) * 64, wn = (wave >> 1) * 64;

    f32x4 acc[4][4];
    #pragma unroll
    for (int a = 0; a < 4; a++)
        #pragma unroll
        for (int b = 0; b < 4; b++) { f32x4 z = {0.f, 0.f, 0.f, 0.f}; acc[a][b] = z; }

    int srow = tid >> 3;          // 0..31
    int skc = (tid & 7) * 8;      // element offset within 64-wide K tile
    const ushort* Abase = A + (size_t)(m0 + srow) * K_DIM + skc;
    const ushort* Bbase = BT + (size_t)(n0 + srow) * K_DIM + skc;
    int ldsoff = (wave * 64) * 8; // wave-uniform LDS chunk base (in ushorts)

    for (int k0 = 0; k0 < K_DIM; k0 += 64) {
        const ushort* ga = Abase + k0;
        const ushort* gb = Bbase + k0;
        #pragma unroll
        for (int i = 0; i < 4; i++) {
            async_copy16(ga + (size_t)i * 32 * K_DIM, As + i * 2048 + ldsoff);
            async_copy16(gb + (size_t)i * 32 * K_DIM, Bs + i * 2048 + ldsoff);
        }
        __syncthreads();
        #pragma unroll
        for (int kk = 0; kk < 64; kk += 32) {
            bf16x8 af[4], bfr[4];
            int koff = kk + ((lane >> 4) * 8);
            #pragma unroll
            for (int a = 0; a < 4; a++) {
                int row = wm + a * 16 + (lane & 15);
                af[a] = *(const bf16x8*)(As + row * 64 + koff);
            }
            #pragma unroll
            for (int b = 0; b < 4; b++) {
                int row = wn + b * 16 + (lane & 15);
                bfr[b] = *(const bf16x8*)(Bs + row * 64 + koff);
            }
            #pragma unroll
            for (int a = 0; a < 4; a++)
                #pragma unroll
                for (int b = 0; b < 4; b++)
                    acc[a][b] = __builtin_amdgcn_mfma_f32_16x16x32_bf16(af[a], bfr[b], acc[a][b], 0, 0, 0);
        }
        __syncthreads();
    }

    int col = lane & 15;
    int rbase = (lane >> 4) * 4;
    #pragma unroll
    for (int a = 0; a < 4; a++) {
        #pragma unroll
        for (int b = 0; b < 4; b++) {
            int gn = n0 + wn + b * 16 + col;
            if (gn < M_COLS) {
                #pragma unroll
                for (int r = 0; r < 4; r++) {
                    int gm = m0 + wm + a * 16 + rbase + r;
                    C[(size_t)gm * M_COLS + gn] = acc[a][b][r];
                }
            }
        }
    }
}

// ---------------- CSR build ----------------
__global__ void k_count(const int* __restrict__ ei, const int* __restrict__ et, int* __restrict__ cnt) {
    int e = blockIdx.x * 256 + threadIdx.x;
    if (e < E_EDGES) {
        int dst = ei[E_EDGES + e];
        int r = et[e];
        atomicAdd(&cnt[dst * R_REL + r], 1);
    }
}

__global__ void k_scan(const int* __restrict__ cnt, int* __restrict__ offs, int* __restrict__ cursor) {
    __shared__ int part[256];
    int t = threadIdx.x;
    const int CH = NSEG / 256;  // 80
    int s = 0;
    for (int i = 0; i < CH; i++) s += cnt[t * CH + i];
    part[t] = s;
    __syncthreads();
    for (int d = 1; d < 256; d <<= 1) {
        int v = (t >= d) ? part[t - d] : 0;
        __syncthreads();
        part[t] += v;
        __syncthreads();
    }
    int run = part[t] - s;   // exclusive prefix
    for (int i = 0; i < CH; i++) {
        int idx = t * CH + i;
        offs[idx] = run;
        cursor[idx] = run;
        run += cnt[idx];
    }
    if (t == 255) offs[NSEG] = run;
}

__global__ void k_fill(const int* __restrict__ ei, const int* __restrict__ et,
                       int* __restrict__ cursor, int* __restrict__ edge_src) {
    int e = blockIdx.x * 256 + threadIdx.x;
    if (e < E_EDGES) {
        int src = ei[e];
        int dst = ei[E_EDGES + e];
        int r = et[e];
        int pos = atomicAdd(&cursor[dst * R_REL + r], 1);
        edge_src[pos] = src;
    }
}

// ---------------- per-node aggregation: feats = sum_r mean_edges h[r,src] + x@root + bias ----------------
__global__ void k_agg(const float* __restrict__ C, const int* __restrict__ offs,
                      const int* __restrict__ edge_src, const float* __restrict__ bias,
                      float* __restrict__ feats) {
    int n = blockIdx.x;
    int t = threadIdx.x;
    if (t >= 125) return;      // 125 * 4 = 500 columns
    f32x4 acc = {0.f, 0.f, 0.f, 0.f};
    #pragma unroll
    for (int r = 0; r < R_REL; r++) {
        int seg = n * R_REL + r;
        int beg = offs[seg], end = offs[seg + 1];
        if (end > beg) {
            f32x4 s = {0.f, 0.f, 0.f, 0.f};
            for (int e = beg; e < end; e++) {
                int src = edge_src[e];
                s += *(const f32x4*)(C + (size_t)src * M_COLS + r * H0 + t * 4);
            }
            float inv = 1.0f / (float)(end - beg);
            acc += s * inv;
        }
    }
    acc += *(const f32x4*)(C + (size_t)n * M_COLS + 5 * H0 + t * 4);
    acc += *(const f32x4*)(bias + t * 4);
    *(f32x4*)(feats + (size_t)n * H0 + t * 4) = acc;
}

// ---------------- FC (feats @ fc_w^T) + per-row BN + ReLU, one wave per row ----------------
__global__ __launch_bounds__(256) void k_fc_bn(const float* __restrict__ feats, const float* __restrict__ fcw,
                                               const float* __restrict__ gu, const float* __restrict__ bu,
                                               const float* __restrict__ gi, const float* __restrict__ bi,
                                               float* __restrict__ out) {
    __shared__ float z[4][80];
    int t = threadIdx.x;
    int lane = t & 63, wave = t >> 6;
    int row = blockIdx.x * 4 + wave;
    float f[8];
    #pragma unroll
    for (int i = 0; i < 8; i++) {
        int k = lane + 64 * i;
        f[i] = (k < H0) ? feats[(size_t)row * H0 + k] : 0.f;
    }
    for (int j = 0; j < H1; j++) {
        float d = 0.f;
        #pragma unroll
        for (int i = 0; i < 8; i++) {
            int k = lane + 64 * i;
            float w = (k < H0) ? fcw[(size_t)j * H0 + k] : 0.f;
            d += f[i] * w;
        }
        #pragma unroll
        for (int s = 32; s > 0; s >>= 1) d += __shfl_xor(d, s);
        if (lane == 0) z[wave][j] = d;
    }
    __syncthreads();
    float a = (lane < H1) ? z[wave][lane] : 0.f;
    float b2 = (lane < H1 - 64) ? z[wave][64 + lane] : 0.f;
    float s1 = a + b2, s2 = a * a + b2 * b2;
    #pragma unroll
    for (int s = 32; s > 0; s >>= 1) { s1 += __shfl_xor(s1, s); s2 += __shfl_xor(s2, s); }
    float mean = s1 / (float)H1;
    float var = s2 / (float)H1 - mean * mean;
    float inv = 1.0f / sqrtf(var + EPS_BN);
    float gamma, beta;
    if (row < U_NODES) { gamma = gu[row];            beta = bu[row]; }
    else               { gamma = gi[row - U_NODES];  beta = bi[row - U_NODES]; }
    if (lane < H1) {
        float v = gamma * (a - mean) * inv + beta;
        out[(size_t)row * H1 + lane] = v > 0.f ? v : 0.f;
    }
    if (lane < H1 - 64) {
        float v = gamma * (b2 - mean) * inv + beta;
        out[(size_t)row * H1 + 64 + lane] = v > 0.f ? v : 0.f;
    }
}

extern "C" void kernel_launch(void* const* d_in, const int* in_sizes, int n_in,
                              void* d_out, int out_size, void* d_ws, size_t ws_size,
                              hipStream_t stream) {
    (void)in_sizes; (void)n_in; (void)out_size; (void)ws_size;
    const float* x         = (const float*)d_in[0];
    const float* basis     = (const float*)d_in[1];
    const float* comp      = (const float*)d_in[2];
    const float* root      = (const float*)d_in[3];
    const float* bias_rgcn = (const float*)d_in[4];
    const float* fc_w      = (const float*)d_in[5];
    const float* gu        = (const float*)d_in[6];
    const float* bu        = (const float*)d_in[7];
    const float* gi        = (const float*)d_in[8];
    const float* bi        = (const float*)d_in[9];
    const int*   ei        = (const int*)d_in[10];
    const int*   et        = (const int*)d_in[11];
    float* out = (float*)d_out;

    char* ws = (char*)d_ws;
    size_t off = 0;
    auto carve = [&](size_t bytes) -> void* {
        void* p = ws + off;
        off += (bytes + 255) & ~(size_t)255;
        return p;
    };
    ushort* xb      = (ushort*)carve((size_t)N_NODES * K_DIM * 2);
    ushort* wallT   = (ushort*)carve((size_t)M_PAD * K_DIM * 2);
    float*  hall    = (float*) carve((size_t)N_NODES * M_COLS * 4);
    float*  feats   = (float*) carve((size_t)N_NODES * H0 * 4);
    int*    cnt     = (int*)   carve((size_t)NSEG * 4);
    int*    offs    = (int*)   carve((size_t)(NSEG + 1) * 4);
    int*    cursor  = (int*)   carve((size_t)NSEG * 4);
    int*    edge_src= (int*)   carve((size_t)E_EDGES * 4);

    hipMemsetAsync(cnt, 0, NSEG * 4, stream);
    k_convert_x<<<16384, 256, 0, stream>>>(x, xb);
    k_make_wallT<<<dim3(128, 16), 256, 0, stream>>>(basis, comp, root, wallT);
    k_count<<<E_EDGES / 256, 256, 0, stream>>>(ei, et, cnt);
    k_scan<<<1, 256, 0, stream>>>(cnt, offs, cursor);
    k_fill<<<E_EDGES / 256, 256, 0, stream>>>(ei, et, cursor, edge_src);
    k_gemm<<<dim3(32, 24), 256, 0, stream>>>(xb, wallT, hall);
    k_agg<<<N_NODES, 128, 0, stream>>>(hall, offs, edge_src, bias_rgcn, feats);
    k_fc_bn<<<N_NODES / 4, 256, 0, stream>>>(feats, fc_w, gu, bu, gi, bi, out);
}

// Round 2
// 666.051 us; speedup vs baseline: 1.1557x; 1.1557x over previous
//
#include <hip/hip_runtime.h>
#include <hip/hip_bf16.h>
#include <stdint.h>

#define N_NODES 4096
#define U_NODES 2048
#define R_REL 5
#define B_BASES 30
#define H0 500
#define H1 75
#define E_EDGES 262144
#define EPS_BN 1e-5f
#define K_DIM 4096
#define M_COLS 3000   // 5*500 (h) + 500 (x@root)
#define M_PAD 3072
#define NSEG (N_NODES*R_REL)  // 20480

typedef __attribute__((ext_vector_type(4))) float f32x4;
typedef __attribute__((ext_vector_type(8))) short bf16x8;

static __device__ __forceinline__ ushort bf16_bits(float f) {
    union { float f; uint32_t u; } c; c.f = f;
    uint32_t u = c.u;
    uint32_t r = (u + 0x7fffu + ((u >> 16) & 1u)) >> 16;   // RNE
    return (ushort)r;
}

static __device__ __forceinline__ void async_copy16(const ushort* g, ushort* l) {
    __builtin_amdgcn_global_load_lds((const __attribute__((address_space(1))) void*)g,
                                     (__attribute__((address_space(3))) void*)l,
                                     16, 0, 0);
}

// ---------------- x fp32 -> bf16 ----------------
__global__ void k_convert_x(const float* __restrict__ x, ushort* __restrict__ xb) {
    int i = (blockIdx.x * 256 + threadIdx.x) * 4;  // N*N divisible by 1024
    float4 v = *(const float4*)(x + i);
    ushort4 o;
    o.x = bf16_bits(v.x); o.y = bf16_bits(v.y);
    o.z = bf16_bits(v.z); o.w = bf16_bits(v.w);
    *(ushort4*)(xb + i) = o;
}

// ---------------- WallT[m][k] bf16, m = r*500+o (r<5: sum_b comp[r,b]*basis[b,k,o]; r=5: root[k,o]) ----------------
__global__ void k_make_wallT(const float* __restrict__ basis, const float* __restrict__ comp,
                             const float* __restrict__ root, ushort* __restrict__ wallT) {
    __shared__ float compl_[R_REL * B_BASES];
    __shared__ float T[32][33];
    int t = threadIdx.x;
    if (t < R_REL * B_BASES) compl_[t] = comp[t];
    __syncthreads();
    int k0 = blockIdx.x * 32, o0 = blockIdx.y * 32;
    int o_in = t & 31, k_in = t >> 5;      // k_in 0..7
    int o = o0 + o_in;
    bool ov = (o < H0);
    float acc[4][6];
    #pragma unroll
    for (int a = 0; a < 4; a++)
        #pragma unroll
        for (int r = 0; r < 6; r++) acc[a][r] = 0.f;
    for (int b = 0; b < B_BASES; b++) {
        float cw[5];
        #pragma unroll
        for (int r = 0; r < 5; r++) cw[r] = compl_[r * B_BASES + b];
        #pragma unroll
        for (int a = 0; a < 4; a++) {
            int k = k0 + a * 8 + k_in;
            float v = ov ? basis[(size_t)b * K_DIM * H0 + (size_t)k * H0 + o] : 0.f;
            #pragma unroll
            for (int r = 0; r < 5; r++) acc[a][r] += cw[r] * v;
        }
    }
    #pragma unroll
    for (int a = 0; a < 4; a++) {
        int k = k0 + a * 8 + k_in;
        acc[a][5] = ov ? root[(size_t)k * H0 + o] : 0.f;
    }
    for (int r = 0; r < 6; r++) {
        __syncthreads();
        #pragma unroll
        for (int a = 0; a < 4; a++) T[o_in][a * 8 + k_in] = acc[a][r];
        __syncthreads();
        int ro = t >> 5, ck = t & 31;
        #pragma unroll
        for (int a = 0; a < 4; a++) {
            int oo = ro + a * 8;
            int om = o0 + oo;
            if (om < H0) {
                int m = r * H0 + om;
                wallT[(size_t)m * K_DIM + k0 + ck] = bf16_bits(T[oo][ck]);
            }
        }
    }
}

// ---------------- GEMM: Hall(4096 x 3000 f32) = xb(4096x4096 bf16) @ WallT^T ----------------
// LDS layout is XOR-swizzled: 16B chunk j of row r holds global chunk j^(r&7).
// Staging side achieves this by permuting WHICH global chunk each lane fetches
// (global_load_lds dest is fixed at base+lane*16); read side applies the same XOR.
__global__ __launch_bounds__(256) void k_gemm(const ushort* __restrict__ A,
                                              const ushort* __restrict__ BT,
                                              float* __restrict__ C) {
    __shared__ __align__(16) ushort As[128 * 64];
    __shared__ __align__(16) ushort Bs[128 * 64];
    int tid = threadIdx.x;
    int lane = tid & 63, wave = tid >> 6;
    int m0 = blockIdx.x * 128, n0 = blockIdx.y * 128;
    int wm = (wave & 1) * 64, wn = (wave >> 1) * 64;

    f32x4 acc[4][4];
    #pragma unroll
    for (int a = 0; a < 4; a++)
        #pragma unroll
        for (int b = 0; b < 4; b++) { f32x4 z = {0.f, 0.f, 0.f, 0.f}; acc[a][b] = z; }

    int srow = tid >> 3;                                  // 0..31
    int skc = (((tid & 7) ^ ((tid >> 3) & 7))) * 8;      // XOR-swizzled k-chunk
    const ushort* Abase = A + (size_t)(m0 + srow) * K_DIM + skc;
    const ushort* Bbase = BT + (size_t)(n0 + srow) * K_DIM + skc;
    int ldsoff = (wave * 64) * 8; // wave-uniform LDS chunk base (in ushorts)

    for (int k0 = 0; k0 < K_DIM; k0 += 64) {
        const ushort* ga = Abase + k0;
        const ushort* gb = Bbase + k0;
        #pragma unroll
        for (int i = 0; i < 4; i++) {
            async_copy16(ga + (size_t)i * 32 * K_DIM, As + i * 2048 + ldsoff);
            async_copy16(gb + (size_t)i * 32 * K_DIM, Bs + i * 2048 + ldsoff);
        }
        __syncthreads();
        #pragma unroll
        for (int kk = 0; kk < 64; kk += 32) {
            bf16x8 af[4], bfr[4];
            int koff = kk + ((lane >> 4) * 8);
            int g = koff >> 3;                            // global chunk 0..7
            #pragma unroll
            for (int a = 0; a < 4; a++) {
                int row = wm + a * 16 + (lane & 15);
                int sw = (g ^ (row & 7)) * 8;
                af[a] = *(const bf16x8*)(As + row * 64 + sw);
            }
            #pragma unroll
            for (int b = 0; b < 4; b++) {
                int row = wn + b * 16 + (lane & 15);
                int sw = (g ^ (row & 7)) * 8;
                bfr[b] = *(const bf16x8*)(Bs + row * 64 + sw);
            }
            #pragma unroll
            for (int a = 0; a < 4; a++)
                #pragma unroll
                for (int b = 0; b < 4; b++)
                    acc[a][b] = __builtin_amdgcn_mfma_f32_16x16x32_bf16(af[a], bfr[b], acc[a][b], 0, 0, 0);
        }
        __syncthreads();
    }

    int col = lane & 15;
    int rbase = (lane >> 4) * 4;
    #pragma unroll
    for (int a = 0; a < 4; a++) {
        #pragma unroll
        for (int b = 0; b < 4; b++) {
            int gn = n0 + wn + b * 16 + col;
            if (gn < M_COLS) {
                #pragma unroll
                for (int r = 0; r < 4; r++) {
                    int gm = m0 + wm + a * 16 + rbase + r;
                    C[(size_t)gm * M_COLS + gn] = acc[a][b][r];
                }
            }
        }
    }
}

// ---------------- CSR build ----------------
__global__ void k_count(const int* __restrict__ ei, const int* __restrict__ et, int* __restrict__ cnt) {
    int e = blockIdx.x * 256 + threadIdx.x;
    if (e < E_EDGES) {
        int dst = ei[E_EDGES + e];
        int r = et[e];
        atomicAdd(&cnt[dst * R_REL + r], 1);
    }
}

__global__ void k_scan(const int* __restrict__ cnt, int* __restrict__ offs, int* __restrict__ cursor) {
    __shared__ int part[256];
    int t = threadIdx.x;
    const int CH = NSEG / 256;  // 80
    int s = 0;
    for (int i = 0; i < CH; i++) s += cnt[t * CH + i];
    part[t] = s;
    __syncthreads();
    for (int d = 1; d < 256; d <<= 1) {
        int v = (t >= d) ? part[t - d] : 0;
        __syncthreads();
        part[t] += v;
        __syncthreads();
    }
    int run = part[t] - s;   // exclusive prefix
    for (int i = 0; i < CH; i++) {
        int idx = t * CH + i;
        offs[idx] = run;
        cursor[idx] = run;
        run += cnt[idx];
    }
    if (t == 255) offs[NSEG] = run;
}

__global__ void k_fill(const int* __restrict__ ei, const int* __restrict__ et,
                       int* __restrict__ cursor, int* __restrict__ edge_src) {
    int e = blockIdx.x * 256 + threadIdx.x;
    if (e < E_EDGES) {
        int src = ei[e];
        int dst = ei[E_EDGES + e];
        int r = et[e];
        int pos = atomicAdd(&cursor[dst * R_REL + r], 1);
        edge_src[pos] = src;
    }
}

// ---------------- per-node aggregation: feats = sum_r mean_edges h[r,src] + x@root + bias ----------------
__global__ void k_agg(const float* __restrict__ C, const int* __restrict__ offs,
                      const int* __restrict__ edge_src, const float* __restrict__ bias,
                      float* __restrict__ feats) {
    int n = blockIdx.x;
    int t = threadIdx.x;
    if (t >= 125) return;      // 125 * 4 = 500 columns
    f32x4 acc = {0.f, 0.f, 0.f, 0.f};
    #pragma unroll
    for (int r = 0; r < R_REL; r++) {
        int seg = n * R_REL + r;
        int beg = offs[seg], end = offs[seg + 1];
        if (end > beg) {
            f32x4 s = {0.f, 0.f, 0.f, 0.f};
            for (int e = beg; e < end; e++) {
                int src = edge_src[e];
                s += *(const f32x4*)(C + (size_t)src * M_COLS + r * H0 + t * 4);
            }
            float inv = 1.0f / (float)(end - beg);
            acc += s * inv;
        }
    }
    acc += *(const f32x4*)(C + (size_t)n * M_COLS + 5 * H0 + t * 4);
    acc += *(const f32x4*)(bias + t * 4);
    *(f32x4*)(feats + (size_t)n * H0 + t * 4) = acc;
}

// ---------------- FC (feats @ fc_w^T) + per-row BN + ReLU, one wave per row ----------------
__global__ __launch_bounds__(256) void k_fc_bn(const float* __restrict__ feats, const float* __restrict__ fcw,
                                               const float* __restrict__ gu, const float* __restrict__ bu,
                                               const float* __restrict__ gi, const float* __restrict__ bi,
                                               float* __restrict__ out) {
    __shared__ float z[4][80];
    int t = threadIdx.x;
    int lane = t & 63, wave = t >> 6;
    int row = blockIdx.x * 4 + wave;
    float f[8];
    #pragma unroll
    for (int i = 0; i < 8; i++) {
        int k = lane + 64 * i;
        f[i] = (k < H0) ? feats[(size_t)row * H0 + k] : 0.f;
    }
    for (int j = 0; j < H1; j++) {
        float d = 0.f;
        #pragma unroll
        for (int i = 0; i < 8; i++) {
            int k = lane + 64 * i;
            float w = (k < H0) ? fcw[(size_t)j * H0 + k] : 0.f;
            d += f[i] * w;
        }
        #pragma unroll
        for (int s = 32; s > 0; s >>= 1) d += __shfl_xor(d, s);
        if (lane == 0) z[wave][j] = d;
    }
    __syncthreads();
    float a = (lane < H1) ? z[wave][lane] : 0.f;
    float b2 = (lane < H1 - 64) ? z[wave][64 + lane] : 0.f;
    float s1 = a + b2, s2 = a * a + b2 * b2;
    #pragma unroll
    for (int s = 32; s > 0; s >>= 1) { s1 += __shfl_xor(s1, s); s2 += __shfl_xor(s2, s); }
    float mean = s1 / (float)H1;
    float var = s2 / (float)H1 - mean * mean;
    float inv = 1.0f / sqrtf(var + EPS_BN);
    float gamma, beta;
    if (row < U_NODES) { gamma = gu[row];            beta = bu[row]; }
    else               { gamma = gi[row - U_NODES];  beta = bi[row - U_NODES]; }
    if (lane < H1) {
        float v = gamma * (a - mean) * inv + beta;
        out[(size_t)row * H1 + lane] = v > 0.f ? v : 0.f;
    }
    if (lane < H1 - 64) {
        float v = gamma * (b2 - mean) * inv + beta;
        out[(size_t)row * H1 + 64 + lane] = v > 0.f ? v : 0.f;
    }
}

extern "C" void kernel_launch(void* const* d_in, const int* in_sizes, int n_in,
                              void* d_out, int out_size, void* d_ws, size_t ws_size,
                              hipStream_t stream) {
    (void)in_sizes; (void)n_in; (void)out_size; (void)ws_size;
    const float* x         = (const float*)d_in[0];
    const float* basis     = (const float*)d_in[1];
    const float* comp      = (const float*)d_in[2];
    const float* root      = (const float*)d_in[3];
    const float* bias_rgcn = (const float*)d_in[4];
    const float* fc_w      = (const float*)d_in[5];
    const float* gu        = (const float*)d_in[6];
    const float* bu        = (const float*)d_in[7];
    const float* gi        = (const float*)d_in[8];
    const float* bi        = (const float*)d_in[9];
    const int*   ei        = (const int*)d_in[10];
    const int*   et        = (const int*)d_in[11];
    float* out = (float*)d_out;

    char* ws = (char*)d_ws;
    size_t off = 0;
    auto carve = [&](size_t bytes) -> void* {
        void* p = ws + off;
        off += (bytes + 255) & ~(size_t)255;
        return p;
    };
    ushort* xb      = (ushort*)carve((size_t)N_NODES * K_DIM * 2);
    ushort* wallT   = (ushort*)carve((size_t)M_PAD * K_DIM * 2);
    float*  hall    = (float*) carve((size_t)N_NODES * M_COLS * 4);
    float*  feats   = (float*) carve((size_t)N_NODES * H0 * 4);
    int*    cnt     = (int*)   carve((size_t)NSEG * 4);
    int*    offs    = (int*)   carve((size_t)(NSEG + 1) * 4);
    int*    cursor  = (int*)   carve((size_t)NSEG * 4);
    int*    edge_src= (int*)   carve((size_t)E_EDGES * 4);

    hipMemsetAsync(cnt, 0, NSEG * 4, stream);
    k_convert_x<<<16384, 256, 0, stream>>>(x, xb);
    k_make_wallT<<<dim3(128, 16), 256, 0, stream>>>(basis, comp, root, wallT);
    k_count<<<E_EDGES / 256, 256, 0, stream>>>(ei, et, cnt);
    k_scan<<<1, 256, 0, stream>>>(cnt, offs, cursor);
    k_fill<<<E_EDGES / 256, 256, 0, stream>>>(ei, et, cursor, edge_src);
    k_gemm<<<dim3(32, 24), 256, 0, stream>>>(xb, wallT, hall);
    k_agg<<<N_NODES, 128, 0, stream>>>(hall, offs, edge_src, bias_rgcn, feats);
    k_fc_bn<<<N_NODES / 4, 256, 0, stream>>>(feats, fc_w, gu, bu, gi, bi, out);
}

// Round 3
// 627.076 us; speedup vs baseline: 1.2275x; 1.0622x over previous
//
#include <hip/hip_runtime.h>
#include <hip/hip_bf16.h>
#include <stdint.h>

#define N_NODES 4096
#define U_NODES 2048
#define R_REL 5
#define B_BASES 30
#define H0 500
#define H1 75
#define E_EDGES 262144
#define EPS_BN 1e-5f
#define K_DIM 4096
#define M_COLS 3000   // 5*500 (h) + 500 (x@root)
#define M_PAD 3072
#define NSEG (N_NODES*R_REL)  // 20480

typedef __attribute__((ext_vector_type(4))) float f32x4;
typedef __attribute__((ext_vector_type(8))) short bf16x8;

static __device__ __forceinline__ ushort bf16_bits(float f) {
    union { float f; uint32_t u; } c; c.f = f;
    uint32_t u = c.u;
    uint32_t r = (u + 0x7fffu + ((u >> 16) & 1u)) >> 16;   // RNE
    return (ushort)r;
}

static __device__ __forceinline__ float bf16_to_f(ushort u) {
    union { uint32_t u; float f; } c; c.u = ((uint32_t)u) << 16; return c.f;
}

static __device__ __forceinline__ void async_copy16(const ushort* g, ushort* l) {
    __builtin_amdgcn_global_load_lds((const __attribute__((address_space(1))) void*)g,
                                     (__attribute__((address_space(3))) void*)l,
                                     16, 0, 0);
}

// ---------------- x fp32 -> bf16 ----------------
__global__ void k_convert_x(const float* __restrict__ x, ushort* __restrict__ xb) {
    int i = (blockIdx.x * 256 + threadIdx.x) * 4;  // N*N divisible by 1024
    float4 v = *(const float4*)(x + i);
    ushort4 o;
    o.x = bf16_bits(v.x); o.y = bf16_bits(v.y);
    o.z = bf16_bits(v.z); o.w = bf16_bits(v.w);
    *(ushort4*)(xb + i) = o;
}

// ---------------- WallT[m][k] bf16, m = r*500+o (r<5: sum_b comp[r,b]*basis[b,k,o]; r=5: root[k,o]) ----------------
__global__ void k_make_wallT(const float* __restrict__ basis, const float* __restrict__ comp,
                             const float* __restrict__ root, ushort* __restrict__ wallT) {
    __shared__ float compl_[R_REL * B_BASES];
    __shared__ float T[32][33];
    int t = threadIdx.x;
    if (t < R_REL * B_BASES) compl_[t] = comp[t];
    __syncthreads();
    int k0 = blockIdx.x * 32, o0 = blockIdx.y * 32;
    int o_in = t & 31, k_in = t >> 5;      // k_in 0..7
    int o = o0 + o_in;
    bool ov = (o < H0);
    float acc[4][6];
    #pragma unroll
    for (int a = 0; a < 4; a++)
        #pragma unroll
        for (int r = 0; r < 6; r++) acc[a][r] = 0.f;
    for (int b = 0; b < B_BASES; b++) {
        float cw[5];
        #pragma unroll
        for (int r = 0; r < 5; r++) cw[r] = compl_[r * B_BASES + b];
        #pragma unroll
        for (int a = 0; a < 4; a++) {
            int k = k0 + a * 8 + k_in;
            float v = ov ? basis[(size_t)b * K_DIM * H0 + (size_t)k * H0 + o] : 0.f;
            #pragma unroll
            for (int r = 0; r < 5; r++) acc[a][r] += cw[r] * v;
        }
    }
    #pragma unroll
    for (int a = 0; a < 4; a++) {
        int k = k0 + a * 8 + k_in;
        acc[a][5] = ov ? root[(size_t)k * H0 + o] : 0.f;
    }
    for (int r = 0; r < 6; r++) {
        __syncthreads();
        #pragma unroll
        for (int a = 0; a < 4; a++) T[o_in][a * 8 + k_in] = acc[a][r];
        __syncthreads();
        int ro = t >> 5, ck = t & 31;
        #pragma unroll
        for (int a = 0; a < 4; a++) {
            int oo = ro + a * 8;
            int om = o0 + oo;
            if (om < H0) {
                int m = r * H0 + om;
                wallT[(size_t)m * K_DIM + k0 + ck] = bf16_bits(T[oo][ck]);
            }
        }
    }
}

// ---------------- GEMM: Hall(4096 x 3000 bf16) = xb(4096x4096 bf16) @ WallT^T ----------------
// LDS layout is XOR-swizzled: 16B chunk j of row r holds global chunk j^(r&7).
__global__ __launch_bounds__(256) void k_gemm(const ushort* __restrict__ A,
                                              const ushort* __restrict__ BT,
                                              ushort* __restrict__ C) {
    __shared__ __align__(16) ushort As[128 * 64];
    __shared__ __align__(16) ushort Bs[128 * 64];
    int tid = threadIdx.x;
    int lane = tid & 63, wave = tid >> 6;
    int m0 = blockIdx.x * 128, n0 = blockIdx.y * 128;
    int wm = (wave & 1) * 64, wn = (wave >> 1) * 64;

    f32x4 acc[4][4];
    #pragma unroll
    for (int a = 0; a < 4; a++)
        #pragma unroll
        for (int b = 0; b < 4; b++) { f32x4 z = {0.f, 0.f, 0.f, 0.f}; acc[a][b] = z; }

    int srow = tid >> 3;                                  // 0..31
    int skc = (((tid & 7) ^ ((tid >> 3) & 7))) * 8;      // XOR-swizzled k-chunk
    const ushort* Abase = A + (size_t)(m0 + srow) * K_DIM + skc;
    const ushort* Bbase = BT + (size_t)(n0 + srow) * K_DIM + skc;
    int ldsoff = (wave * 64) * 8; // wave-uniform LDS chunk base (in ushorts)

    for (int k0 = 0; k0 < K_DIM; k0 += 64) {
        const ushort* ga = Abase + k0;
        const ushort* gb = Bbase + k0;
        #pragma unroll
        for (int i = 0; i < 4; i++) {
            async_copy16(ga + (size_t)i * 32 * K_DIM, As + i * 2048 + ldsoff);
            async_copy16(gb + (size_t)i * 32 * K_DIM, Bs + i * 2048 + ldsoff);
        }
        __syncthreads();
        #pragma unroll
        for (int kk = 0; kk < 64; kk += 32) {
            bf16x8 af[4], bfr[4];
            int koff = kk + ((lane >> 4) * 8);
            int g = koff >> 3;                            // global chunk 0..7
            #pragma unroll
            for (int a = 0; a < 4; a++) {
                int row = wm + a * 16 + (lane & 15);
                int sw = (g ^ (row & 7)) * 8;
                af[a] = *(const bf16x8*)(As + row * 64 + sw);
            }
            #pragma unroll
            for (int b = 0; b < 4; b++) {
                int row = wn + b * 16 + (lane & 15);
                int sw = (g ^ (row & 7)) * 8;
                bfr[b] = *(const bf16x8*)(Bs + row * 64 + sw);
            }
            #pragma unroll
            for (int a = 0; a < 4; a++)
                #pragma unroll
                for (int b = 0; b < 4; b++)
                    acc[a][b] = __builtin_amdgcn_mfma_f32_16x16x32_bf16(af[a], bfr[b], acc[a][b], 0, 0, 0);
        }
        __syncthreads();
    }

    int col = lane & 15;
    int rbase = (lane >> 4) * 4;
    #pragma unroll
    for (int a = 0; a < 4; a++) {
        #pragma unroll
        for (int b = 0; b < 4; b++) {
            int gn = n0 + wn + b * 16 + col;
            if (gn < M_COLS) {
                #pragma unroll
                for (int r = 0; r < 4; r++) {
                    int gm = m0 + wm + a * 16 + rbase + r;
                    C[(size_t)gm * M_COLS + gn] = bf16_bits(acc[a][b][r]);
                }
            }
        }
    }
}

// ---------------- CSR build ----------------
__global__ void k_count(const int* __restrict__ ei, const int* __restrict__ et, int* __restrict__ cnt) {
    int e = blockIdx.x * 256 + threadIdx.x;
    if (e < E_EDGES) {
        int dst = ei[E_EDGES + e];
        int r = et[e];
        atomicAdd(&cnt[dst * R_REL + r], 1);
    }
}

__global__ void k_scan(const int* __restrict__ cnt, int* __restrict__ offs, int* __restrict__ cursor) {
    __shared__ int part[256];
    int t = threadIdx.x;
    const int CH = NSEG / 256;  // 80
    int s = 0;
    for (int i = 0; i < CH; i++) s += cnt[t * CH + i];
    part[t] = s;
    __syncthreads();
    for (int d = 1; d < 256; d <<= 1) {
        int v = (t >= d) ? part[t - d] : 0;
        __syncthreads();
        part[t] += v;
        __syncthreads();
    }
    int run = part[t] - s;   // exclusive prefix
    for (int i = 0; i < CH; i++) {
        int idx = t * CH + i;
        offs[idx] = run;
        cursor[idx] = run;
        run += cnt[idx];
    }
    if (t == 255) offs[NSEG] = run;
}

__global__ void k_fill(const int* __restrict__ ei, const int* __restrict__ et,
                       int* __restrict__ cursor, int* __restrict__ edge_src) {
    int e = blockIdx.x * 256 + threadIdx.x;
    if (e < E_EDGES) {
        int src = ei[e];
        int dst = ei[E_EDGES + e];
        int r = et[e];
        int pos = atomicAdd(&cursor[dst * R_REL + r], 1);
        edge_src[pos] = src;
    }
}

// ---------------- per-node aggregation: feats = sum_r mean_edges h[r,src] + x@root + bias ----------------
__global__ void k_agg(const ushort* __restrict__ C, const int* __restrict__ offs,
                      const int* __restrict__ edge_src, const float* __restrict__ bias,
                      float* __restrict__ feats) {
    int n = blockIdx.x;
    int t = threadIdx.x;
    if (t >= 125) return;      // 125 * 4 = 500 columns
    f32x4 acc = {0.f, 0.f, 0.f, 0.f};
    #pragma unroll
    for (int r = 0; r < R_REL; r++) {
        int seg = n * R_REL + r;
        int beg = offs[seg], end = offs[seg + 1];
        if (end > beg) {
            f32x4 s = {0.f, 0.f, 0.f, 0.f};
            for (int e = beg; e < end; e++) {
                int src = edge_src[e];
                ushort4 v = *(const ushort4*)(C + (size_t)src * M_COLS + r * H0 + t * 4);
                s.x += bf16_to_f(v.x); s.y += bf16_to_f(v.y);
                s.z += bf16_to_f(v.z); s.w += bf16_to_f(v.w);
            }
            float inv = 1.0f / (float)(end - beg);
            acc += s * inv;
        }
    }
    {
        ushort4 v = *(const ushort4*)(C + (size_t)n * M_COLS + 5 * H0 + t * 4);
        acc.x += bf16_to_f(v.x); acc.y += bf16_to_f(v.y);
        acc.z += bf16_to_f(v.z); acc.w += bf16_to_f(v.w);
    }
    acc += *(const f32x4*)(bias + t * 4);
    *(f32x4*)(feats + (size_t)n * H0 + t * 4) = acc;
}

// ---------------- FC (feats @ fc_w^T) + per-row BN + ReLU, 4 rows per block ----------------
__global__ __launch_bounds__(128) void k_fc_bn(const float* __restrict__ feats, const float* __restrict__ fcw,
                                               const float* __restrict__ gu, const float* __restrict__ bu,
                                               const float* __restrict__ gi, const float* __restrict__ bi,
                                               float* __restrict__ out) {
    __shared__ float fs[4][H0];
    __shared__ float z[4][80];
    int t = threadIdx.x;
    int row0 = blockIdx.x * 4;
    if (t < 125) {
        #pragma unroll
        for (int r = 0; r < 4; r++)
            *(f32x4*)&fs[r][t * 4] = *(const f32x4*)(feats + (size_t)(row0 + r) * H0 + t * 4);
    }
    __syncthreads();
    if (t < H1) {
        float a0 = 0.f, a1 = 0.f, a2 = 0.f, a3 = 0.f;
        const float* wr = fcw + (size_t)t * H0;
        for (int k = 0; k < H0; k += 4) {
            float4 w = *(const float4*)(wr + k);
            a0 += w.x * fs[0][k] + w.y * fs[0][k+1] + w.z * fs[0][k+2] + w.w * fs[0][k+3];
            a1 += w.x * fs[1][k] + w.y * fs[1][k+1] + w.z * fs[1][k+2] + w.w * fs[1][k+3];
            a2 += w.x * fs[2][k] + w.y * fs[2][k+1] + w.z * fs[2][k+2] + w.w * fs[2][k+3];
            a3 += w.x * fs[3][k] + w.y * fs[3][k+1] + w.z * fs[3][k+2] + w.w * fs[3][k+3];
        }
        z[0][t] = a0; z[1][t] = a1; z[2][t] = a2; z[3][t] = a3;
    }
    __syncthreads();
    int lane = t & 63, wave = t >> 6;   // 2 waves, each handles 2 rows
    #pragma unroll
    for (int rr = 0; rr < 2; rr++) {
        int r = wave * 2 + rr;
        int row = row0 + r;
        float a = (lane < H1) ? z[r][lane] : 0.f;
        float b2 = (lane < H1 - 64) ? z[r][64 + lane] : 0.f;
        float s1 = a + b2, s2 = a * a + b2 * b2;
        #pragma unroll
        for (int s = 32; s > 0; s >>= 1) { s1 += __shfl_xor(s1, s); s2 += __shfl_xor(s2, s); }
        float mean = s1 / (float)H1;
        float var = s2 / (float)H1 - mean * mean;
        float inv = 1.0f / sqrtf(var + EPS_BN);
        float gamma, beta;
        if (row < U_NODES) { gamma = gu[row];            beta = bu[row]; }
        else               { gamma = gi[row - U_NODES];  beta = bi[row - U_NODES]; }
        if (lane < H1) {
            float v = gamma * (a - mean) * inv + beta;
            out[(size_t)row * H1 + lane] = v > 0.f ? v : 0.f;
        }
        if (lane < H1 - 64) {
            float v = gamma * (b2 - mean) * inv + beta;
            out[(size_t)row * H1 + 64 + lane] = v > 0.f ? v : 0.f;
        }
    }
}

extern "C" void kernel_launch(void* const* d_in, const int* in_sizes, int n_in,
                              void* d_out, int out_size, void* d_ws, size_t ws_size,
                              hipStream_t stream) {
    (void)in_sizes; (void)n_in; (void)out_size; (void)ws_size;
    const float* x         = (const float*)d_in[0];
    const float* basis     = (const float*)d_in[1];
    const float* comp      = (const float*)d_in[2];
    const float* root      = (const float*)d_in[3];
    const float* bias_rgcn = (const float*)d_in[4];
    const float* fc_w      = (const float*)d_in[5];
    const float* gu        = (const float*)d_in[6];
    const float* bu        = (const float*)d_in[7];
    const float* gi        = (const float*)d_in[8];
    const float* bi        = (const float*)d_in[9];
    const int*   ei        = (const int*)d_in[10];
    const int*   et        = (const int*)d_in[11];
    float* out = (float*)d_out;

    char* ws = (char*)d_ws;
    size_t off = 0;
    auto carve = [&](size_t bytes) -> void* {
        void* p = ws + off;
        off += (bytes + 255) & ~(size_t)255;
        return p;
    };
    ushort* xb      = (ushort*)carve((size_t)N_NODES * K_DIM * 2);
    ushort* wallT   = (ushort*)carve((size_t)M_PAD * K_DIM * 2);
    ushort* hall    = (ushort*)carve((size_t)N_NODES * M_COLS * 2);
    float*  feats   = (float*) carve((size_t)N_NODES * H0 * 4);
    int*    cnt     = (int*)   carve((size_t)NSEG * 4);
    int*    offs    = (int*)   carve((size_t)(NSEG + 1) * 4);
    int*    cursor  = (int*)   carve((size_t)NSEG * 4);
    int*    edge_src= (int*)   carve((size_t)E_EDGES * 4);

    hipMemsetAsync(cnt, 0, NSEG * 4, stream);
    k_convert_x<<<16384, 256, 0, stream>>>(x, xb);
    k_make_wallT<<<dim3(128, 16), 256, 0, stream>>>(basis, comp, root, wallT);
    k_count<<<E_EDGES / 256, 256, 0, stream>>>(ei, et, cnt);
    k_scan<<<1, 256, 0, stream>>>(cnt, offs, cursor);
    k_fill<<<E_EDGES / 256, 256, 0, stream>>>(ei, et, cursor, edge_src);
    k_gemm<<<dim3(32, 24), 256, 0, stream>>>(xb, wallT, hall);
    k_agg<<<N_NODES, 128, 0, stream>>>(hall, offs, edge_src, bias_rgcn, feats);
    k_fc_bn<<<N_NODES / 4, 128, 0, stream>>>(feats, fc_w, gu, bu, gi, bi, out);
}

// Round 4
// 626.450 us; speedup vs baseline: 1.2287x; 1.0010x over previous
//
#include <hip/hip_runtime.h>
#include <hip/hip_bf16.h>
#include <stdint.h>

#define N_NODES 4096
#define U_NODES 2048
#define R_REL 5
#define B_BASES 30
#define H0 500
#define H1 75
#define E_EDGES 262144
#define EPS_BN 1e-5f
#define K_DIM 4096
#define M_COLS 3000   // 5*500 (h) + 500 (x@root)
#define M_PAD 3072
#define NSEG (N_NODES*R_REL)  // 20480

typedef __attribute__((ext_vector_type(4))) float f32x4;
typedef __attribute__((ext_vector_type(8))) short bf16x8;

static __device__ __forceinline__ ushort bf16_bits(float f) {
    union { float f; uint32_t u; } c; c.f = f;
    uint32_t u = c.u;
    uint32_t r = (u + 0x7fffu + ((u >> 16) & 1u)) >> 16;   // RNE
    return (ushort)r;
}

static __device__ __forceinline__ float bf16_to_f(ushort u) {
    union { uint32_t u; float f; } c; c.u = ((uint32_t)u) << 16; return c.f;
}

static __device__ __forceinline__ void async_copy16(const ushort* g, ushort* l) {
    __builtin_amdgcn_global_load_lds((const __attribute__((address_space(1))) void*)g,
                                     (__attribute__((address_space(3))) void*)l,
                                     16, 0, 0);
}

// ---------------- x fp32 -> bf16 ----------------
__global__ void k_convert_x(const float* __restrict__ x, ushort* __restrict__ xb) {
    int i = (blockIdx.x * 256 + threadIdx.x) * 4;  // N*N divisible by 1024
    float4 v = *(const float4*)(x + i);
    ushort4 o;
    o.x = bf16_bits(v.x); o.y = bf16_bits(v.y);
    o.z = bf16_bits(v.z); o.w = bf16_bits(v.w);
    *(ushort4*)(xb + i) = o;
}

// ---------------- WallT[m][k] bf16, m = r*500+o (r<5: sum_b comp[r,b]*basis[b,k,o]; r=5: root[k,o]) ----------------
__global__ void k_make_wallT(const float* __restrict__ basis, const float* __restrict__ comp,
                             const float* __restrict__ root, ushort* __restrict__ wallT) {
    __shared__ float compl_[R_REL * B_BASES];
    __shared__ float T[32][33];
    int t = threadIdx.x;
    if (t < R_REL * B_BASES) compl_[t] = comp[t];
    __syncthreads();
    int k0 = blockIdx.x * 32, o0 = blockIdx.y * 32;
    int o_in = t & 31, k_in = t >> 5;      // k_in 0..7
    int o = o0 + o_in;
    bool ov = (o < H0);
    float acc[4][6];
    #pragma unroll
    for (int a = 0; a < 4; a++)
        #pragma unroll
        for (int r = 0; r < 6; r++) acc[a][r] = 0.f;
    for (int b = 0; b < B_BASES; b++) {
        float cw[5];
        #pragma unroll
        for (int r = 0; r < 5; r++) cw[r] = compl_[r * B_BASES + b];
        #pragma unroll
        for (int a = 0; a < 4; a++) {
            int k = k0 + a * 8 + k_in;
            float v = ov ? basis[(size_t)b * K_DIM * H0 + (size_t)k * H0 + o] : 0.f;
            #pragma unroll
            for (int r = 0; r < 5; r++) acc[a][r] += cw[r] * v;
        }
    }
    #pragma unroll
    for (int a = 0; a < 4; a++) {
        int k = k0 + a * 8 + k_in;
        acc[a][5] = ov ? root[(size_t)k * H0 + o] : 0.f;
    }
    for (int r = 0; r < 6; r++) {
        __syncthreads();
        #pragma unroll
        for (int a = 0; a < 4; a++) T[o_in][a * 8 + k_in] = acc[a][r];
        __syncthreads();
        int ro = t >> 5, ck = t & 31;
        #pragma unroll
        for (int a = 0; a < 4; a++) {
            int oo = ro + a * 8;
            int om = o0 + oo;
            if (om < H0) {
                int m = r * H0 + om;
                wallT[(size_t)m * K_DIM + k0 + ck] = bf16_bits(T[oo][ck]);
            }
        }
    }
}

// ---------------- GEMM: Hall(4096 x 3000 bf16) = xb(4096x4096 bf16) @ WallT^T ----------------
// LDS layout is XOR-swizzled: 16B chunk j of row r holds global chunk j^(r&7).
// Block order is XCD-aware: xcd = bid&7 owns 3 contiguous n-panels so each
// XCD's 4MB L2 keeps its 3MB B-slab resident while streaming A.
__global__ __launch_bounds__(256) void k_gemm(const ushort* __restrict__ A,
                                              const ushort* __restrict__ BT,
                                              ushort* __restrict__ C) {
    __shared__ __align__(16) ushort As[128 * 64];
    __shared__ __align__(16) ushort Bs[128 * 64];
    int tid = threadIdx.x;
    int lane = tid & 63, wave = tid >> 6;
    int bid = blockIdx.x;              // 768 linear
    int xcd = bid & 7;
    int j = bid >> 3;                  // 0..95
    int n_t = xcd * 3 + (j >> 5);      // 0..23
    int m_t = j & 31;                  // 0..31
    int m0 = m_t * 128, n0 = n_t * 128;
    int wm = (wave & 1) * 64, wn = (wave >> 1) * 64;

    f32x4 acc[4][4];
    #pragma unroll
    for (int a = 0; a < 4; a++)
        #pragma unroll
        for (int b = 0; b < 4; b++) { f32x4 z = {0.f, 0.f, 0.f, 0.f}; acc[a][b] = z; }

    int srow = tid >> 3;                                  // 0..31
    int skc = (((tid & 7) ^ ((tid >> 3) & 7))) * 8;      // XOR-swizzled k-chunk
    const ushort* Abase = A + (size_t)(m0 + srow) * K_DIM + skc;
    const ushort* Bbase = BT + (size_t)(n0 + srow) * K_DIM + skc;
    int ldsoff = (wave * 64) * 8; // wave-uniform LDS chunk base (in ushorts)

    for (int k0 = 0; k0 < K_DIM; k0 += 64) {
        const ushort* ga = Abase + k0;
        const ushort* gb = Bbase + k0;
        #pragma unroll
        for (int i = 0; i < 4; i++) {
            async_copy16(ga + (size_t)i * 32 * K_DIM, As + i * 2048 + ldsoff);
            async_copy16(gb + (size_t)i * 32 * K_DIM, Bs + i * 2048 + ldsoff);
        }
        __syncthreads();
        #pragma unroll
        for (int kk = 0; kk < 64; kk += 32) {
            bf16x8 af[4], bfr[4];
            int koff = kk + ((lane >> 4) * 8);
            int g = koff >> 3;                            // global chunk 0..7
            #pragma unroll
            for (int a = 0; a < 4; a++) {
                int row = wm + a * 16 + (lane & 15);
                int sw = (g ^ (row & 7)) * 8;
                af[a] = *(const bf16x8*)(As + row * 64 + sw);
            }
            #pragma unroll
            for (int b = 0; b < 4; b++) {
                int row = wn + b * 16 + (lane & 15);
                int sw = (g ^ (row & 7)) * 8;
                bfr[b] = *(const bf16x8*)(Bs + row * 64 + sw);
            }
            #pragma unroll
            for (int a = 0; a < 4; a++)
                #pragma unroll
                for (int b = 0; b < 4; b++)
                    acc[a][b] = __builtin_amdgcn_mfma_f32_16x16x32_bf16(af[a], bfr[b], acc[a][b], 0, 0, 0);
        }
        __syncthreads();
    }

    int col = lane & 15;
    int rbase = (lane >> 4) * 4;
    #pragma unroll
    for (int a = 0; a < 4; a++) {
        #pragma unroll
        for (int b = 0; b < 4; b++) {
            int gn = n0 + wn + b * 16 + col;
            if (gn < M_COLS) {
                #pragma unroll
                for (int r = 0; r < 4; r++) {
                    int gm = m0 + wm + a * 16 + rbase + r;
                    C[(size_t)gm * M_COLS + gn] = bf16_bits(acc[a][b][r]);
                }
            }
        }
    }
}

// ---------------- CSR build ----------------
__global__ void k_count(const int* __restrict__ ei, const int* __restrict__ et, int* __restrict__ cnt) {
    int e = blockIdx.x * 256 + threadIdx.x;
    if (e < E_EDGES) {
        int dst = ei[E_EDGES + e];
        int r = et[e];
        atomicAdd(&cnt[dst * R_REL + r], 1);
    }
}

__global__ void k_scan(const int* __restrict__ cnt, int* __restrict__ offs, int* __restrict__ cursor) {
    __shared__ int part[256];
    int t = threadIdx.x;
    const int CH = NSEG / 256;  // 80
    int s = 0;
    for (int i = 0; i < CH; i++) s += cnt[t * CH + i];
    part[t] = s;
    __syncthreads();
    for (int d = 1; d < 256; d <<= 1) {
        int v = (t >= d) ? part[t - d] : 0;
        __syncthreads();
        part[t] += v;
        __syncthreads();
    }
    int run = part[t] - s;   // exclusive prefix
    for (int i = 0; i < CH; i++) {
        int idx = t * CH + i;
        offs[idx] = run;
        cursor[idx] = run;
        run += cnt[idx];
    }
    if (t == 255) offs[NSEG] = run;
}

__global__ void k_fill(const int* __restrict__ ei, const int* __restrict__ et,
                       int* __restrict__ cursor, int* __restrict__ edge_src) {
    int e = blockIdx.x * 256 + threadIdx.x;
    if (e < E_EDGES) {
        int src = ei[e];
        int dst = ei[E_EDGES + e];
        int r = et[e];
        int pos = atomicAdd(&cursor[dst * R_REL + r], 1);
        edge_src[pos] = src;
    }
}

// ---------------- per-node aggregation: feats = sum_r mean_edges h[r,src] + x@root + bias ----------------
__global__ void k_agg(const ushort* __restrict__ C, const int* __restrict__ offs,
                      const int* __restrict__ edge_src, const float* __restrict__ bias,
                      float* __restrict__ feats) {
    int n = blockIdx.x;
    int t = threadIdx.x;
    if (t >= 125) return;      // 125 * 4 = 500 columns
    f32x4 acc = {0.f, 0.f, 0.f, 0.f};
    #pragma unroll
    for (int r = 0; r < R_REL; r++) {
        int seg = n * R_REL + r;
        int beg = offs[seg], end = offs[seg + 1];
        if (end > beg) {
            f32x4 s0 = {0.f, 0.f, 0.f, 0.f};
            f32x4 s1 = {0.f, 0.f, 0.f, 0.f};
            const ushort* Cr = C + r * H0 + t * 4;
            int e = beg;
            for (; e + 1 < end; e += 2) {
                int srcA = edge_src[e];
                int srcB = edge_src[e + 1];
                ushort4 va = *(const ushort4*)(Cr + (size_t)srcA * M_COLS);
                ushort4 vb = *(const ushort4*)(Cr + (size_t)srcB * M_COLS);
                s0.x += bf16_to_f(va.x); s0.y += bf16_to_f(va.y);
                s0.z += bf16_to_f(va.z); s0.w += bf16_to_f(va.w);
                s1.x += bf16_to_f(vb.x); s1.y += bf16_to_f(vb.y);
                s1.z += bf16_to_f(vb.z); s1.w += bf16_to_f(vb.w);
            }
            if (e < end) {
                int srcA = edge_src[e];
                ushort4 va = *(const ushort4*)(Cr + (size_t)srcA * M_COLS);
                s0.x += bf16_to_f(va.x); s0.y += bf16_to_f(va.y);
                s0.z += bf16_to_f(va.z); s0.w += bf16_to_f(va.w);
            }
            f32x4 s = s0 + s1;
            float inv = 1.0f / (float)(end - beg);
            acc += s * inv;
        }
    }
    {
        ushort4 v = *(const ushort4*)(C + (size_t)n * M_COLS + 5 * H0 + t * 4);
        acc.x += bf16_to_f(v.x); acc.y += bf16_to_f(v.y);
        acc.z += bf16_to_f(v.z); acc.w += bf16_to_f(v.w);
    }
    acc += *(const f32x4*)(bias + t * 4);
    *(f32x4*)(feats + (size_t)n * H0 + t * 4) = acc;
}

// ---------------- FC (feats @ fc_w^T) + per-row BN + ReLU, 4 rows per block ----------------
__global__ __launch_bounds__(128) void k_fc_bn(const float* __restrict__ feats, const float* __restrict__ fcw,
                                               const float* __restrict__ gu, const float* __restrict__ bu,
                                               const float* __restrict__ gi, const float* __restrict__ bi,
                                               float* __restrict__ out) {
    __shared__ float fs[4][H0];
    __shared__ float z[4][80];
    int t = threadIdx.x;
    int row0 = blockIdx.x * 4;
    if (t < 125) {
        #pragma unroll
        for (int r = 0; r < 4; r++)
            *(f32x4*)&fs[r][t * 4] = *(const f32x4*)(feats + (size_t)(row0 + r) * H0 + t * 4);
    }
    __syncthreads();
    if (t < H1) {
        float a0 = 0.f, a1 = 0.f, a2 = 0.f, a3 = 0.f;
        const float* wr = fcw + (size_t)t * H0;
        for (int k = 0; k < H0; k += 4) {
            float4 w = *(const float4*)(wr + k);
            a0 += w.x * fs[0][k] + w.y * fs[0][k+1] + w.z * fs[0][k+2] + w.w * fs[0][k+3];
            a1 += w.x * fs[1][k] + w.y * fs[1][k+1] + w.z * fs[1][k+2] + w.w * fs[1][k+3];
            a2 += w.x * fs[2][k] + w.y * fs[2][k+1] + w.z * fs[2][k+2] + w.w * fs[2][k+3];
            a3 += w.x * fs[3][k] + w.y * fs[3][k+1] + w.z * fs[3][k+2] + w.w * fs[3][k+3];
        }
        z[0][t] = a0; z[1][t] = a1; z[2][t] = a2; z[3][t] = a3;
    }
    __syncthreads();
    int lane = t & 63, wave = t >> 6;   // 2 waves, each handles 2 rows
    #pragma unroll
    for (int rr = 0; rr < 2; rr++) {
        int r = wave * 2 + rr;
        int row = row0 + r;
        float a = (lane < H1) ? z[r][lane] : 0.f;
        float b2 = (lane < H1 - 64) ? z[r][64 + lane] : 0.f;
        float s1 = a + b2, s2 = a * a + b2 * b2;
        #pragma unroll
        for (int s = 32; s > 0; s >>= 1) { s1 += __shfl_xor(s1, s); s2 += __shfl_xor(s2, s); }
        float mean = s1 / (float)H1;
        float var = s2 / (float)H1 - mean * mean;
        float inv = 1.0f / sqrtf(var + EPS_BN);
        float gamma, beta;
        if (row < U_NODES) { gamma = gu[row];            beta = bu[row]; }
        else               { gamma = gi[row - U_NODES];  beta = bi[row - U_NODES]; }
        if (lane < H1) {
            float v = gamma * (a - mean) * inv + beta;
            out[(size_t)row * H1 + lane] = v > 0.f ? v : 0.f;
        }
        if (lane < H1 - 64) {
            float v = gamma * (b2 - mean) * inv + beta;
            out[(size_t)row * H1 + 64 + lane] = v > 0.f ? v : 0.f;
        }
    }
}

extern "C" void kernel_launch(void* const* d_in, const int* in_sizes, int n_in,
                              void* d_out, int out_size, void* d_ws, size_t ws_size,
                              hipStream_t stream) {
    (void)in_sizes; (void)n_in; (void)out_size; (void)ws_size;
    const float* x         = (const float*)d_in[0];
    const float* basis     = (const float*)d_in[1];
    const float* comp      = (const float*)d_in[2];
    const float* root      = (const float*)d_in[3];
    const float* bias_rgcn = (const float*)d_in[4];
    const float* fc_w      = (const float*)d_in[5];
    const float* gu        = (const float*)d_in[6];
    const float* bu        = (const float*)d_in[7];
    const float* gi        = (const float*)d_in[8];
    const float* bi        = (const float*)d_in[9];
    const int*   ei        = (const int*)d_in[10];
    const int*   et        = (const int*)d_in[11];
    float* out = (float*)d_out;

    char* ws = (char*)d_ws;
    size_t off = 0;
    auto carve = [&](size_t bytes) -> void* {
        void* p = ws + off;
        off += (bytes + 255) & ~(size_t)255;
        return p;
    };
    ushort* xb      = (ushort*)carve((size_t)N_NODES * K_DIM * 2);
    ushort* wallT   = (ushort*)carve((size_t)M_PAD * K_DIM * 2);
    ushort* hall    = (ushort*)carve((size_t)N_NODES * M_COLS * 2);
    float*  feats   = (float*) carve((size_t)N_NODES * H0 * 4);
    int*    cnt     = (int*)   carve((size_t)NSEG * 4);
    int*    offs    = (int*)   carve((size_t)(NSEG + 1) * 4);
    int*    cursor  = (int*)   carve((size_t)NSEG * 4);
    int*    edge_src= (int*)   carve((size_t)E_EDGES * 4);

    hipMemsetAsync(cnt, 0, NSEG * 4, stream);
    k_convert_x<<<16384, 256, 0, stream>>>(x, xb);
    k_make_wallT<<<dim3(128, 16), 256, 0, stream>>>(basis, comp, root, wallT);
    k_count<<<E_EDGES / 256, 256, 0, stream>>>(ei, et, cnt);
    k_scan<<<1, 256, 0, stream>>>(cnt, offs, cursor);
    k_fill<<<E_EDGES / 256, 256, 0, stream>>>(ei, et, cursor, edge_src);
    k_gemm<<<768, 256, 0, stream>>>(xb, wallT, hall);
    k_agg<<<N_NODES, 128, 0, stream>>>(hall, offs, edge_src, bias_rgcn, feats);
    k_fc_bn<<<N_NODES / 4, 128, 0, stream>>>(feats, fc_w, gu, bu, gi, bi, out);
}

// Round 5
// 623.955 us; speedup vs baseline: 1.2336x; 1.0040x over previous
//
#include <hip/hip_runtime.h>
#include <hip/hip_bf16.h>
#include <stdint.h>

#define N_NODES 4096
#define U_NODES 2048
#define R_REL 5
#define B_BASES 30
#define H0 500
#define H1 75
#define E_EDGES 262144
#define EPS_BN 1e-5f
#define K_DIM 4096
#define M_COLS 3000   // 5*500 (h) + 500 (x@root)
#define M_PAD 3072
#define NSEG (N_NODES*R_REL)  // 20480

typedef __attribute__((ext_vector_type(4))) float f32x4;
typedef __attribute__((ext_vector_type(8))) short bf16x8;

static __device__ __forceinline__ ushort bf16_bits(float f) {
    union { float f; uint32_t u; } c; c.f = f;
    uint32_t u = c.u;
    uint32_t r = (u + 0x7fffu + ((u >> 16) & 1u)) >> 16;   // RNE
    return (ushort)r;
}

static __device__ __forceinline__ float bf16_to_f(ushort u) {
    union { uint32_t u; float f; } c; c.u = ((uint32_t)u) << 16; return c.f;
}

static __device__ __forceinline__ void fma_u4(f32x4& s, float w, ushort4 v) {
    s.x += w * bf16_to_f(v.x); s.y += w * bf16_to_f(v.y);
    s.z += w * bf16_to_f(v.z); s.w += w * bf16_to_f(v.w);
}

static __device__ __forceinline__ void async_copy16(const ushort* g, ushort* l) {
    __builtin_amdgcn_global_load_lds((const __attribute__((address_space(1))) void*)g,
                                     (__attribute__((address_space(3))) void*)l,
                                     16, 0, 0);
}

// ---------------- x fp32 -> bf16 (+ zero cnt, folds the memset dispatch) ----------------
__global__ void k_convert_x(const float* __restrict__ x, ushort* __restrict__ xb,
                            int* __restrict__ cnt) {
    int gid = blockIdx.x * 256 + threadIdx.x;
    if (gid < NSEG) cnt[gid] = 0;
    int i = gid * 4;  // N*N divisible by 1024
    float4 v = *(const float4*)(x + i);
    ushort4 o;
    o.x = bf16_bits(v.x); o.y = bf16_bits(v.y);
    o.z = bf16_bits(v.z); o.w = bf16_bits(v.w);
    *(ushort4*)(xb + i) = o;
}

// ---------------- WallT[m][k] bf16, m = r*500+o (r<5: sum_b comp[r,b]*basis[b,k,o]; r=5: root[k,o]) ----------------
__global__ void k_make_wallT(const float* __restrict__ basis, const float* __restrict__ comp,
                             const float* __restrict__ root, ushort* __restrict__ wallT) {
    __shared__ float compl_[R_REL * B_BASES];
    __shared__ float T[32][33];
    int t = threadIdx.x;
    if (t < R_REL * B_BASES) compl_[t] = comp[t];
    __syncthreads();
    int k0 = blockIdx.x * 32, o0 = blockIdx.y * 32;
    int o_in = t & 31, k_in = t >> 5;      // k_in 0..7
    int o = o0 + o_in;
    bool ov = (o < H0);
    float acc[4][6];
    #pragma unroll
    for (int a = 0; a < 4; a++)
        #pragma unroll
        for (int r = 0; r < 6; r++) acc[a][r] = 0.f;
    for (int b = 0; b < B_BASES; b++) {
        float cw[5];
        #pragma unroll
        for (int r = 0; r < 5; r++) cw[r] = compl_[r * B_BASES + b];
        #pragma unroll
        for (int a = 0; a < 4; a++) {
            int k = k0 + a * 8 + k_in;
            float v = ov ? basis[(size_t)b * K_DIM * H0 + (size_t)k * H0 + o] : 0.f;
            #pragma unroll
            for (int r = 0; r < 5; r++) acc[a][r] += cw[r] * v;
        }
    }
    #pragma unroll
    for (int a = 0; a < 4; a++) {
        int k = k0 + a * 8 + k_in;
        acc[a][5] = ov ? root[(size_t)k * H0 + o] : 0.f;
    }
    for (int r = 0; r < 6; r++) {
        __syncthreads();
        #pragma unroll
        for (int a = 0; a < 4; a++) T[o_in][a * 8 + k_in] = acc[a][r];
        __syncthreads();
        int ro = t >> 5, ck = t & 31;
        #pragma unroll
        for (int a = 0; a < 4; a++) {
            int oo = ro + a * 8;
            int om = o0 + oo;
            if (om < H0) {
                int m = r * H0 + om;
                wallT[(size_t)m * K_DIM + k0 + ck] = bf16_bits(T[oo][ck]);
            }
        }
    }
}

// ---------------- GEMM: Hall(4096 x 3000 bf16) = xb(4096x4096 bf16) @ WallT^T ----------------
// LDS layout is XOR-swizzled: 16B chunk j of row r holds global chunk j^(r&7).
__global__ __launch_bounds__(256) void k_gemm(const ushort* __restrict__ A,
                                              const ushort* __restrict__ BT,
                                              ushort* __restrict__ C) {
    __shared__ __align__(16) ushort As[128 * 64];
    __shared__ __align__(16) ushort Bs[128 * 64];
    int tid = threadIdx.x;
    int lane = tid & 63, wave = tid >> 6;
    int bid = blockIdx.x;              // 768 linear
    int xcd = bid & 7;
    int j = bid >> 3;                  // 0..95
    int n_t = xcd * 3 + (j >> 5);      // 0..23
    int m_t = j & 31;                  // 0..31
    int m0 = m_t * 128, n0 = n_t * 128;
    int wm = (wave & 1) * 64, wn = (wave >> 1) * 64;

    f32x4 acc[4][4];
    #pragma unroll
    for (int a = 0; a < 4; a++)
        #pragma unroll
        for (int b = 0; b < 4; b++) { f32x4 z = {0.f, 0.f, 0.f, 0.f}; acc[a][b] = z; }

    int srow = tid >> 3;                                  // 0..31
    int skc = (((tid & 7) ^ ((tid >> 3) & 7))) * 8;      // XOR-swizzled k-chunk
    const ushort* Abase = A + (size_t)(m0 + srow) * K_DIM + skc;
    const ushort* Bbase = BT + (size_t)(n0 + srow) * K_DIM + skc;
    int ldsoff = (wave * 64) * 8; // wave-uniform LDS chunk base (in ushorts)

    for (int k0 = 0; k0 < K_DIM; k0 += 64) {
        const ushort* ga = Abase + k0;
        const ushort* gb = Bbase + k0;
        #pragma unroll
        for (int i = 0; i < 4; i++) {
            async_copy16(ga + (size_t)i * 32 * K_DIM, As + i * 2048 + ldsoff);
            async_copy16(gb + (size_t)i * 32 * K_DIM, Bs + i * 2048 + ldsoff);
        }
        __syncthreads();
        #pragma unroll
        for (int kk = 0; kk < 64; kk += 32) {
            bf16x8 af[4], bfr[4];
            int koff = kk + ((lane >> 4) * 8);
            int g = koff >> 3;                            // global chunk 0..7
            #pragma unroll
            for (int a = 0; a < 4; a++) {
                int row = wm + a * 16 + (lane & 15);
                int sw = (g ^ (row & 7)) * 8;
                af[a] = *(const bf16x8*)(As + row * 64 + sw);
            }
            #pragma unroll
            for (int b = 0; b < 4; b++) {
                int row = wn + b * 16 + (lane & 15);
                int sw = (g ^ (row & 7)) * 8;
                bfr[b] = *(const bf16x8*)(Bs + row * 64 + sw);
            }
            #pragma unroll
            for (int a = 0; a < 4; a++)
                #pragma unroll
                for (int b = 0; b < 4; b++)
                    acc[a][b] = __builtin_amdgcn_mfma_f32_16x16x32_bf16(af[a], bfr[b], acc[a][b], 0, 0, 0);
        }
        __syncthreads();
    }

    int col = lane & 15;
    int rbase = (lane >> 4) * 4;
    #pragma unroll
    for (int a = 0; a < 4; a++) {
        #pragma unroll
        for (int b = 0; b < 4; b++) {
            int gn = n0 + wn + b * 16 + col;
            if (gn < M_COLS) {
                #pragma unroll
                for (int r = 0; r < 4; r++) {
                    int gm = m0 + wm + a * 16 + rbase + r;
                    C[(size_t)gm * M_COLS + gn] = bf16_bits(acc[a][b][r]);
                }
            }
        }
    }
}

// ---------------- CSR build ----------------
__global__ void k_count(const int* __restrict__ ei, const int* __restrict__ et, int* __restrict__ cnt) {
    int e = blockIdx.x * 256 + threadIdx.x;
    if (e < E_EDGES) {
        int dst = ei[E_EDGES + e];
        int r = et[e];
        atomicAdd(&cnt[dst * R_REL + r], 1);
    }
}

// single block; int4-vectorized loads/stores (80 ints per thread = 20 int4)
__global__ void k_scan(const int* __restrict__ cnt, int* __restrict__ offs, int* __restrict__ cursor) {
    __shared__ int part[256];
    int t = threadIdx.x;
    int4 buf[20];
    const int4* c4 = (const int4*)(cnt + t * 80);
    int s = 0;
    #pragma unroll
    for (int i = 0; i < 20; i++) { buf[i] = c4[i]; s += buf[i].x + buf[i].y + buf[i].z + buf[i].w; }
    part[t] = s;
    __syncthreads();
    for (int d = 1; d < 256; d <<= 1) {
        int v = (t >= d) ? part[t - d] : 0;
        __syncthreads();
        part[t] += v;
        __syncthreads();
    }
    int run = part[t] - s;   // exclusive prefix
    int4* o4 = (int4*)(offs + t * 80);
    int4* u4 = (int4*)(cursor + t * 80);
    #pragma unroll
    for (int i = 0; i < 20; i++) {
        int4 c = buf[i];
        int4 o;
        o.x = run; o.y = run + c.x; o.z = run + c.x + c.y; o.w = run + c.x + c.y + c.z;
        run += c.x + c.y + c.z + c.w;
        o4[i] = o; u4[i] = o;
    }
    if (t == 255) offs[NSEG] = run;
}

// fill emits packed (src<<3)|r plus per-edge weight 1/cnt[seg]
__global__ void k_fill(const int* __restrict__ ei, const int* __restrict__ et,
                       const int* __restrict__ offs, int* __restrict__ cursor,
                       int* __restrict__ edge_val, float* __restrict__ edge_w) {
    int e = blockIdx.x * 256 + threadIdx.x;
    if (e < E_EDGES) {
        int src = ei[e];
        int dst = ei[E_EDGES + e];
        int r = et[e];
        int seg = dst * R_REL + r;
        int pos = atomicAdd(&cursor[seg], 1);
        edge_val[pos] = (src << 3) | r;
        edge_w[pos] = 1.0f / (float)(offs[seg + 1] - offs[seg]);
    }
}

// ---------------- per-node aggregation: one flat weighted loop over the node's edges ----------------
__global__ void k_agg(const ushort* __restrict__ C, const int* __restrict__ offs,
                      const int* __restrict__ edge_val, const float* __restrict__ edge_w,
                      const float* __restrict__ bias, float* __restrict__ feats) {
    int n = blockIdx.x;
    int t = threadIdx.x;
    if (t >= 125) return;      // 125 * 4 = 500 columns
    int beg = offs[n * R_REL];
    int end = offs[n * R_REL + R_REL];
    f32x4 s0 = {0.f,0.f,0.f,0.f}, s1 = {0.f,0.f,0.f,0.f};
    f32x4 s2 = {0.f,0.f,0.f,0.f}, s3 = {0.f,0.f,0.f,0.f};
    const ushort* Ct = C + t * 4;
    int e = beg;
    for (; e + 3 < end; e += 4) {
        int   v0 = edge_val[e],   v1 = edge_val[e+1], v2 = edge_val[e+2], v3 = edge_val[e+3];
        float w0 = edge_w[e],     w1 = edge_w[e+1],   w2 = edge_w[e+2],   w3 = edge_w[e+3];
        ushort4 a0 = *(const ushort4*)(Ct + (size_t)(v0 >> 3) * M_COLS + (v0 & 7) * H0);
        ushort4 a1 = *(const ushort4*)(Ct + (size_t)(v1 >> 3) * M_COLS + (v1 & 7) * H0);
        ushort4 a2 = *(const ushort4*)(Ct + (size_t)(v2 >> 3) * M_COLS + (v2 & 7) * H0);
        ushort4 a3 = *(const ushort4*)(Ct + (size_t)(v3 >> 3) * M_COLS + (v3 & 7) * H0);
        fma_u4(s0, w0, a0); fma_u4(s1, w1, a1); fma_u4(s2, w2, a2); fma_u4(s3, w3, a3);
    }
    for (; e < end; e++) {
        int v = edge_val[e];
        float w = edge_w[e];
        ushort4 a = *(const ushort4*)(Ct + (size_t)(v >> 3) * M_COLS + (v & 7) * H0);
        fma_u4(s0, w, a);
    }
    f32x4 acc = (s0 + s1) + (s2 + s3);
    {
        ushort4 v = *(const ushort4*)(C + (size_t)n * M_COLS + 5 * H0 + t * 4);
        acc.x += bf16_to_f(v.x); acc.y += bf16_to_f(v.y);
        acc.z += bf16_to_f(v.z); acc.w += bf16_to_f(v.w);
    }
    acc += *(const f32x4*)(bias + t * 4);
    *(f32x4*)(feats + (size_t)n * H0 + t * 4) = acc;
}

// ---------------- FC (feats @ fc_w^T) + per-row BN + ReLU, 4 rows per block ----------------
__global__ __launch_bounds__(128) void k_fc_bn(const float* __restrict__ feats, const float* __restrict__ fcw,
                                               const float* __restrict__ gu, const float* __restrict__ bu,
                                               const float* __restrict__ gi, const float* __restrict__ bi,
                                               float* __restrict__ out) {
    __shared__ float fs[4][H0];
    __shared__ float z[4][80];
    int t = threadIdx.x;
    int row0 = blockIdx.x * 4;
    if (t < 125) {
        #pragma unroll
        for (int r = 0; r < 4; r++)
            *(f32x4*)&fs[r][t * 4] = *(const f32x4*)(feats + (size_t)(row0 + r) * H0 + t * 4);
    }
    __syncthreads();
    if (t < H1) {
        float a0 = 0.f, a1 = 0.f, a2 = 0.f, a3 = 0.f;
        const float* wr = fcw + (size_t)t * H0;
        for (int k = 0; k < H0; k += 4) {
            float4 w = *(const float4*)(wr + k);
            a0 += w.x * fs[0][k] + w.y * fs[0][k+1] + w.z * fs[0][k+2] + w.w * fs[0][k+3];
            a1 += w.x * fs[1][k] + w.y * fs[1][k+1] + w.z * fs[1][k+2] + w.w * fs[1][k+3];
            a2 += w.x * fs[2][k] + w.y * fs[2][k+1] + w.z * fs[2][k+2] + w.w * fs[2][k+3];
            a3 += w.x * fs[3][k] + w.y * fs[3][k+1] + w.z * fs[3][k+2] + w.w * fs[3][k+3];
        }
        z[0][t] = a0; z[1][t] = a1; z[2][t] = a2; z[3][t] = a3;
    }
    __syncthreads();
    int lane = t & 63, wave = t >> 6;   // 2 waves, each handles 2 rows
    #pragma unroll
    for (int rr = 0; rr < 2; rr++) {
        int r = wave * 2 + rr;
        int row = row0 + r;
        float a = (lane < H1) ? z[r][lane] : 0.f;
        float b2 = (lane < H1 - 64) ? z[r][64 + lane] : 0.f;
        float s1 = a + b2, s2 = a * a + b2 * b2;
        #pragma unroll
        for (int s = 32; s > 0; s >>= 1) { s1 += __shfl_xor(s1, s); s2 += __shfl_xor(s2, s); }
        float mean = s1 / (float)H1;
        float var = s2 / (float)H1 - mean * mean;
        float inv = 1.0f / sqrtf(var + EPS_BN);
        float gamma, beta;
        if (row < U_NODES) { gamma = gu[row];            beta = bu[row]; }
        else               { gamma = gi[row - U_NODES];  beta = bi[row - U_NODES]; }
        if (lane < H1) {
            float v = gamma * (a - mean) * inv + beta;
            out[(size_t)row * H1 + lane] = v > 0.f ? v : 0.f;
        }
        if (lane < H1 - 64) {
            float v = gamma * (b2 - mean) * inv + beta;
            out[(size_t)row * H1 + 64 + lane] = v > 0.f ? v : 0.f;
        }
    }
}

extern "C" void kernel_launch(void* const* d_in, const int* in_sizes, int n_in,
                              void* d_out, int out_size, void* d_ws, size_t ws_size,
                              hipStream_t stream) {
    (void)in_sizes; (void)n_in; (void)out_size; (void)ws_size;
    const float* x         = (const float*)d_in[0];
    const float* basis     = (const float*)d_in[1];
    const float* comp      = (const float*)d_in[2];
    const float* root      = (const float*)d_in[3];
    const float* bias_rgcn = (const float*)d_in[4];
    const float* fc_w      = (const float*)d_in[5];
    const float* gu        = (const float*)d_in[6];
    const float* bu        = (const float*)d_in[7];
    const float* gi        = (const float*)d_in[8];
    const float* bi        = (const float*)d_in[9];
    const int*   ei        = (const int*)d_in[10];
    const int*   et        = (const int*)d_in[11];
    float* out = (float*)d_out;

    char* ws = (char*)d_ws;
    size_t off = 0;
    auto carve = [&](size_t bytes) -> void* {
        void* p = ws + off;
        off += (bytes + 255) & ~(size_t)255;
        return p;
    };
    ushort* xb      = (ushort*)carve((size_t)N_NODES * K_DIM * 2);
    ushort* wallT   = (ushort*)carve((size_t)M_PAD * K_DIM * 2);
    ushort* hall    = (ushort*)carve((size_t)N_NODES * M_COLS * 2);
    float*  feats   = (float*) carve((size_t)N_NODES * H0 * 4);
    int*    cnt     = (int*)   carve((size_t)NSEG * 4);
    int*    offs    = (int*)   carve((size_t)(NSEG + 1) * 4);
    int*    cursor  = (int*)   carve((size_t)NSEG * 4);
    int*    edge_val= (int*)   carve((size_t)E_EDGES * 4);
    float*  edge_w  = (float*) carve((size_t)E_EDGES * 4);

    k_convert_x<<<16384, 256, 0, stream>>>(x, xb, cnt);
    k_make_wallT<<<dim3(128, 16), 256, 0, stream>>>(basis, comp, root, wallT);
    k_count<<<E_EDGES / 256, 256, 0, stream>>>(ei, et, cnt);
    k_scan<<<1, 256, 0, stream>>>(cnt, offs, cursor);
    k_fill<<<E_EDGES / 256, 256, 0, stream>>>(ei, et, offs, cursor, edge_val, edge_w);
    k_gemm<<<768, 256, 0, stream>>>(xb, wallT, hall);
    k_agg<<<N_NODES, 128, 0, stream>>>(hall, offs, edge_val, edge_w, bias_rgcn, feats);
    k_fc_bn<<<N_NODES / 4, 128, 0, stream>>>(feats, fc_w, gu, bu, gi, bi, out);
}